// Round 12
// baseline (71.488 us; speedup 1.0000x reference)
//
#include <hip/hip_runtime.h>

#define GDIM 38
#define GG   (GDIM * GDIM)          // 1444
#define TOTAL (GDIM * GDIM * GDIM)  // 54872
#define HALF  (TOTAL / 2)           // 27436 buckets per half
#define HWORDS (HALF / 2)           // 13718 packed u32 words per half
#define NSLICE 64                   // atom slices for histogram

typedef float f32x4 __attribute__((ext_vector_type(4)));

// packed (disp+1) per k: dx | dy<<8 | dz<<16
__device__ __constant__ unsigned int c_dp[13] = {
    // {-1,0,0},{-1,-1,0},{0,-1,0},{1,-1,0},{-1,1,-1},{0,1,-1},{1,1,-1},
    // {-1,0,-1},{0,0,-1},{1,0,-1},{-1,-1,-1},{0,-1,-1},{1,-1,-1}
    0x010100u, 0x010000u, 0x010001u, 0x010002u,
    0x000200u, 0x000201u, 0x000202u,
    0x000100u, 0x000101u, 0x000102u,
    0x000000u, 0x000001u, 0x000002u};

// translation-case LUT indexed by cx*9+cy*3+cz, cat: 0=low(0), 1=mid, 2=high(G+1)
__device__ __constant__ unsigned char c_case[27] = {
    11,  2, 0,   8,  1, 0,   5, 14, 0,
    12,  3, 0,   9,  0, 0,   6, 15, 0,
    13,  4, 0,  10, 17, 0,   7, 16, 0};

#define BS 256

// K1: frac + flat only. Wave-private LDS staging (3 KB), barrier-free.
__global__ __launch_bounds__(BS) void frac_kernel(
    const float* __restrict__ coords, const float* __restrict__ cell,
    float* __restrict__ out, int N)
{
    __shared__ float s[768];                // 4 waves × 192 floats
    const int tid  = threadIdx.x;
    const int w    = tid >> 6;
    const int lane = tid & 63;
    const long long wbase = (long long)blockIdx.x * BS + 64 * w;
    if (wbase >= N) return;

    float* sc = s + 192 * w;
    const long long OFF1 = 3LL * N;

    const bool fullwave = (wbase + 64 <= N);
    const int nval = fullwave ? 64 : (int)(N - wbase);

    if (fullwave) {
        const f32x4* src = (const f32x4*)(coords + wbase * 3);
        if (lane < 48) ((f32x4*)sc)[lane] = src[lane];
    } else {
        const float* src = coords + wbase * 3;
        for (int j = lane; j < nval * 3; j += 64) sc[j] = src[j];
    }

    if (lane < nval) {
        int v[3];
#pragma unroll
        for (int a = 0; a < 3; ++a) {
            float d = cell[4 * a];              // diagonal
            float f = sc[3 * lane + a] / d;     // IEEE divide, matches jnp
            f = f - floorf(f);
            if (f >= 1.0f) f -= 1.0f;
            if (f < 0.0f)  f += 1.0f;
            sc[3 * lane + a] = f;               // frac in place
            v[a] = (int)floorf(f * (float)GDIM);
        }
        int flat = v[0] * GG + v[1] * GDIM + v[2];
        __builtin_nontemporal_store((float)flat, &out[OFF1 + wbase + lane]);
    }

    if (fullwave) {
        f32x4* dfr = (f32x4*)(out + wbase * 3);
        if (lane < 48) __builtin_nontemporal_store(((f32x4*)sc)[lane], &dfr[lane]);
    } else {
        float* dfr = out + wbase * 3;
        for (int j = lane; j < nval * 3; j += 64)
            __builtin_nontemporal_store(sc[j], &dfr[j]);
    }
}

// K2: neighbors, indexed by OUTPUT position. No LDS; thread j owns f32x4 j of
// both nf and nc streams. Atom info re-derived from flat[] (L2-resident).
__global__ __launch_bounds__(BS) void neigh_kernel(
    const float* __restrict__ flatf, float* __restrict__ outnf,
    float* __restrict__ outnc, int N)
{
    const long long M = 13LL * N;
    const long long j = (long long)blockIdx.x * BS + threadIdx.x;
    const long long idx0 = 4 * j;
    if (idx0 >= M) return;

    const int i0 = (int)(idx0 / 13);
    int i3 = (int)((idx0 + 3) / 13);
    if (i3 >= N) i3 = N - 1;

    const int f0 = (int)flatf[i0];
    const int f3 = (int)flatf[i3];
    const int v0a = f0 / GG, r0 = f0 - v0a * GG;
    const int v1a = r0 / GDIM, v2a = r0 - v1a * GDIM;
    const int v0b = f3 / GG, r1 = f3 - v0b * GG;
    const int v1b = r1 / GDIM, v2b = r1 - v1b * GDIM;

    float nf[4], nc[4];
#pragma unroll
    for (int e = 0; e < 4; ++e) {
        const long long idx = idx0 + e;
        const int i = (int)(idx / 13);
        const int k = (int)(idx - 13LL * i);
        const int va0 = (i == i0) ? v0a : v0b;
        const int va1 = (i == i0) ? v1a : v1b;
        const int va2 = (i == i0) ? v2a : v2b;
        const unsigned int dp = c_dp[k];
        const int n0 = va0 + (int)(dp & 0xFFu);
        const int n1 = va1 + (int)((dp >> 8) & 0xFFu);
        const int n2 = va2 + (int)((dp >> 16) & 0xFFu);
        const int cat0 = (n0 == 0) ? 0 : ((n0 == GDIM + 1) ? 2 : 1);
        const int cat1 = (n1 == 0) ? 0 : ((n1 == GDIM + 1) ? 2 : 1);
        const int cat2 = (n2 == 0) ? 0 : ((n2 == GDIM + 1) ? 2 : 1);
        const int m0 = (n0 == 0) ? (GDIM - 1) : ((n0 == GDIM + 1) ? 0 : n0 - 1);
        const int m1 = (n1 == 0) ? (GDIM - 1) : ((n1 == GDIM + 1) ? 0 : n1 - 1);
        const int m2 = (n2 == 0) ? (GDIM - 1) : ((n2 == GDIM + 1) ? 0 : n2 - 1);
        nf[e] = (float)(m0 * GG + m1 * GDIM + m2);
        nc[e] = (float)c_case[cat0 * 9 + cat1 * 3 + cat2];
    }

    if (idx0 + 3 < M) {
        __builtin_nontemporal_store(*(const f32x4*)nf, &((f32x4*)outnf)[j]);
        __builtin_nontemporal_store(*(const f32x4*)nc, &((f32x4*)outnc)[j]);
    } else {
        for (int e = 0; e < 4 && idx0 + e < M; ++e) {
            __builtin_nontemporal_store(nf[e], &outnf[idx0 + e]);
            __builtin_nontemporal_store(nc[e], &outnc[idx0 + e]);
        }
    }
}

// LDS-packed-u16 histogram. 128 blocks = (slice s = b>>1) x (half h = b&1).
__global__ __launch_bounds__(1024) void hist_kernel(
    const float* __restrict__ flatf, unsigned int* __restrict__ parts, int N)
{
    __shared__ unsigned int h[HWORDS];       // 54.9 KB
    const int t = threadIdx.x;
    const int half = blockIdx.x & 1;
    const int slice = blockIdx.x >> 1;
    const int lo = half * HALF;

    for (int j = t; j < HWORDS; j += 1024) h[j] = 0u;
    __syncthreads();

    for (long long i = (long long)slice * 1024 + t; i < N;
         i += (long long)NSLICE * 1024) {
        int flat = (int)flatf[i] - lo;
        if ((unsigned)flat < (unsigned)HALF)
            atomicAdd(&h[flat >> 1], 1u << ((flat & 1) * 16));
    }
    __syncthreads();

    unsigned int* dst = parts + (long long)blockIdx.x * HWORDS;
    for (int j = t; j < HWORDS; j += 1024)
        __builtin_nontemporal_store(h[j], &dst[j]);
}

// collapse NSLICE slices per (half, word), unpack u16 pairs -> cnt + count
__global__ __launch_bounds__(256) void reduce_kernel(
    const unsigned int* __restrict__ parts, int* __restrict__ cnt,
    float* __restrict__ out_count)
{
    int j = blockIdx.x * 256 + threadIdx.x;  // word index in [0, HWORDS)
    if (j >= HWORDS) return;
#pragma unroll
    for (int half = 0; half < 2; ++half) {
        unsigned int sum = 0;
        for (int s = 0; s < NSLICE; ++s)
            sum += parts[(long long)(2 * s + half) * HWORDS + j];
        int b = half * HALF + 2 * j;
        int c0 = (int)(sum & 0xFFFFu), c1 = (int)(sum >> 16);
        cnt[b]     = c0;
        cnt[b + 1] = c1;
        out_count[b]     = (float)c0;
        out_count[b + 1] = (float)c1;
    }
}

// parallel scan — 54 blocks; each sums everything before its range
__global__ __launch_bounds__(1024) void scan_kernel(
    const int* __restrict__ cnt, float* __restrict__ out_cum)
{
    __shared__ int lds[1024];
    const int t = threadIdx.x;
    const int base = blockIdx.x * 1024;

    int pre = 0;
    for (int j = t; j < base; j += 1024) pre += cnt[j];
    lds[t] = pre;
    __syncthreads();
    for (int off = 512; off > 0; off >>= 1) {
        if (t < off) lds[t] += lds[t + off];
        __syncthreads();
    }
    const int blockpre = lds[0];
    __syncthreads();

    const int idx = base + t;
    const int c = (idx < TOTAL) ? cnt[idx] : 0;

    lds[t] = c;
    __syncthreads();
    for (int off = 1; off < 1024; off <<= 1) {
        int vprev = (t >= off) ? lds[t - off] : 0;
        __syncthreads();
        lds[t] += vprev;
        __syncthreads();
    }
    const int exc = lds[t] - c;

    if (idx < TOTAL)
        __builtin_nontemporal_store((float)(blockpre + exc), &out_cum[idx]);
}

extern "C" void kernel_launch(void* const* d_in, const int* in_sizes, int n_in,
                              void* d_out, int out_size, void* d_ws, size_t ws_size,
                              hipStream_t stream)
{
    const float* coords = (const float*)d_in[0];
    const float* cell   = (const float*)d_in[1];
    float* out = (float*)d_out;
    unsigned int* parts = (unsigned int*)d_ws;           // 128*HWORDS u32 = 7 MB
    int* cnt = (int*)(parts + 2LL * NSLICE * HWORDS);

    // out_size = 30N + 2*TOTAL
    int N = (int)((out_size - 2 * TOTAL) / 30);

    frac_kernel<<<(N + BS - 1) / BS, BS, 0, stream>>>(coords, cell, out, N);

    const long long M = 13LL * N;
    const long long nthr = (M + 3) / 4;
    neigh_kernel<<<(int)((nthr + BS - 1) / BS), BS, 0, stream>>>(
        out + 3LL * N, out + 4LL * N, out + 17LL * N, N);

    long long off4 = 30LL * N;  // count then cumcount at the tail
    hist_kernel<<<2 * NSLICE, 1024, 0, stream>>>(out + 3LL * N, parts, N);
    reduce_kernel<<<(HWORDS + 255) / 256, 256, 0, stream>>>(parts, cnt, out + off4);
    scan_kernel<<<(TOTAL + 1023) / 1024, 1024, 0, stream>>>(cnt, out + off4 + TOTAL);
}